// Round 8
// baseline (208.175 us; speedup 1.0000x reference)
//
#include <hip/hip_runtime.h>
#include <hip/hip_bf16.h>

#define BB 4
#define NS 16384
#define NG 2048
#define DD 128
#define SPLITG 16
#define C2F (-0.23083120f)  // -log2(e)/sigma^2

typedef short bf16x8 __attribute__((ext_vector_type(8)));
typedef unsigned short u16x8 __attribute__((ext_vector_type(8)));
typedef float f32x4 __attribute__((ext_vector_type(4)));
typedef float f32x16 __attribute__((ext_vector_type(16)));
typedef int i32x4 __attribute__((ext_vector_type(4)));

// r4-exact exp2: builtin (compiler-known hazards) or libcall. NEVER naked asm.
#if __has_builtin(__builtin_amdgcn_exp2f)
#define EXP2(x) __builtin_amdgcn_exp2f(x)
#else
#define EXP2(x) exp2f(x)
#endif

__device__ __forceinline__ unsigned short f2bf(float x) {
  unsigned int u = __builtin_bit_cast(unsigned int, x);
  u += 0x7FFFu + ((u >> 16) & 1u);
  return (unsigned short)(u >> 16);
}
__device__ __forceinline__ float bf2f(unsigned short h) {
  unsigned int u = ((unsigned int)h) << 16;
  return __builtin_bit_cast(float, u);
}

// pack 8 f32 -> bf16x8 A-fragment via cvt_pk + permlane32_swap (T12 recipe).
// HARDENED: single asm block, earlyclobber outputs (outputs written while
// later inputs still pending), s_nop guards around the cross-lane permlane
// (write->permlane-read and permlane-write->VALU-read wait states are
// invisible to the compiler inside asm).
#define PACK_SWAP(e0, e1, e2, e3, e4, e5, e6, e7, OUT)                        \
  {                                                                           \
    unsigned pq0, pq1, pq2, pq3;                                              \
    asm("v_cvt_pk_bf16_f32 %0, %4, %5\n\t"                                    \
        "v_cvt_pk_bf16_f32 %1, %6, %7\n\t"                                    \
        "v_cvt_pk_bf16_f32 %2, %8, %9\n\t"                                    \
        "v_cvt_pk_bf16_f32 %3, %10, %11\n\t"                                  \
        "s_nop 1\n\t"                                                         \
        "v_permlane32_swap_b32 %0, %2\n\t"                                    \
        "v_permlane32_swap_b32 %1, %3\n\t"                                    \
        "s_nop 1"                                                             \
        : "=&v"(pq0), "=&v"(pq1), "=&v"(pq2), "=&v"(pq3)                      \
        : "v"(e0), "v"(e1), "v"(e2), "v"(e3), "v"(e4), "v"(e5), "v"(e6),      \
          "v"(e7));                                                           \
    i32x4 tmp_ = {(int)pq0, (int)pq1, (int)pq2, (int)pq3};                    \
    OUT = __builtin_bit_cast(bf16x8, tmp_);                                   \
  }

// ---------------------------------------------------------------------------
// prep: node pos encodings (UNSCALED verified form: dot(pos1,pos2)=d2, hi/lo
// split) + weight transposes, fused into one launch.
// ---------------------------------------------------------------------------
__device__ __forceinline__ void posprep1(const float* __restrict__ v, int i,
                                         unsigned short* __restrict__ pos1,
                                         unsigned short* __restrict__ pos2) {
  float x = v[i * 3 + 0], y = v[i * 3 + 1], z = v[i * 3 + 2];
  unsigned short hx = f2bf(x), hy = f2bf(y), hz = f2bf(z);
  float fx = bf2f(hx), fy = bf2f(hy), fz = bf2f(hz);
  unsigned short lx = f2bf(x - fx), ly = f2bf(y - fy), lz = f2bf(z - fz);
  float n = x * x + y * y + z * z;
  unsigned short nh = f2bf(n);
  unsigned short nl = f2bf(n - bf2f(nh));
  unsigned short m2hx = f2bf(-2.f * fx), m2hy = f2bf(-2.f * fy),
                 m2hz = f2bf(-2.f * fz);
  unsigned short m2lx = f2bf(-2.f * bf2f(lx)), m2ly = f2bf(-2.f * bf2f(ly)),
                 m2lz = f2bf(-2.f * bf2f(lz));
  const unsigned short one = 0x3F80;
  u16x8 a0 = {m2hx, m2hy, m2hz, m2lx, m2ly, m2lz, m2hx, m2hy};
  u16x8 a1 = {m2hz, m2lx, m2ly, m2lz, nh, nl, one, one};
  u16x8 b0 = {hx, hy, hz, hx, hy, hz, lx, ly};
  u16x8 b1 = {lz, lx, ly, lz, one, one, nh, nl};
  *(u16x8*)(pos1 + (long)i * 16) = a0;
  *(u16x8*)(pos1 + (long)i * 16 + 8) = a1;
  *(u16x8*)(pos2 + (long)i * 16) = b0;
  *(u16x8*)(pos2 + (long)i * 16 + 8) = b1;
}

__global__ __launch_bounds__(256) void prep_k(
    const float* __restrict__ vs, const float* __restrict__ vg,
    const float* __restrict__ Ws_pre, const float* __restrict__ Wg_pre,
    const float* __restrict__ Ws_post, const float* __restrict__ Wg_post,
    unsigned short* __restrict__ pos1_s, unsigned short* __restrict__ pos2_s,
    unsigned short* __restrict__ pos1_g, unsigned short* __restrict__ pos2_g,
    unsigned short* __restrict__ WtS_pre, unsigned short* __restrict__ WtG_pre,
    unsigned short* __restrict__ WtS_post,
    unsigned short* __restrict__ WtG_post) {
  const int NODEBLK = (BB * (NS + NG)) / 256;  // 288
  int bid = blockIdx.x, tid = threadIdx.x;
  if (bid < NODEBLK) {
    int i = bid * 256 + tid;
    if (i < BB * NS)
      posprep1(vs, i, pos1_s, pos2_s);
    else
      posprep1(vg, i - BB * NS, pos1_g, pos2_g);
  } else {
    int k2 = (bid - NODEBLK) * 256 + tid;
    const float* W;
    unsigned short* Wt;
    int kshift, loc;
    if (k2 < 16384) { W = Ws_pre; Wt = WtS_pre; kshift = 7; loc = k2; }
    else if (k2 < 32768) { W = Wg_pre; Wt = WtG_pre; kshift = 7; loc = k2 - 16384; }
    else if (k2 < 65536) { W = Ws_post; Wt = WtS_post; kshift = 8; loc = k2 - 32768; }
    else { W = Wg_post; Wt = WtG_post; kshift = 8; loc = k2 - 65536; }
    int K = 1 << kshift;
    int e = loc >> kshift, k = loc & (K - 1);
    Wt[(long)e * K + k] = f2bf(W[(long)k * 128 + e]);
  }
}

// ---------------------------------------------------------------------------
// pre GEMM (surface + graph fused): H = relu(X @ W + b), K=128.
// ---------------------------------------------------------------------------
__global__ __launch_bounds__(256) void pre_mfma_k(
    const float* __restrict__ xs, const float* __restrict__ xg,
    const unsigned short* __restrict__ WtS,
    const unsigned short* __restrict__ WtG, const float* __restrict__ bs,
    const float* __restrict__ bg, unsigned short* __restrict__ xs_h,
    unsigned short* __restrict__ xg_h) {
  long r0 = (long)blockIdx.x * 64;
  const float* X;
  const unsigned short* Wt;
  const float* bias;
  unsigned short* H;
  long row0;
  if (r0 < (long)BB * NS) {
    X = xs; Wt = WtS; bias = bs; H = xs_h; row0 = r0;
  } else {
    X = xg; Wt = WtG; bias = bg; H = xg_h; row0 = r0 - (long)BB * NS;
  }
  int tid = threadIdx.x, l = tid & 63, w = tid >> 6;
  int g = l >> 4, r = l & 15;
  row0 += w * 16;
  const float* xrow = X + (row0 + r) * DD;
  f32x4 z4 = {0.f, 0.f, 0.f, 0.f};
  f32x4 acc[8];
#pragma unroll
  for (int i = 0; i < 8; ++i) acc[i] = z4;
#pragma unroll
  for (int ks = 0; ks < 4; ++ks) {
    float4 v0 = *(const float4*)(xrow + ks * 32 + 8 * g);
    float4 v1 = *(const float4*)(xrow + ks * 32 + 8 * g + 4);
    bf16x8 a;
    a[0] = (short)f2bf(v0.x); a[1] = (short)f2bf(v0.y);
    a[2] = (short)f2bf(v0.z); a[3] = (short)f2bf(v0.w);
    a[4] = (short)f2bf(v1.x); a[5] = (short)f2bf(v1.y);
    a[6] = (short)f2bf(v1.z); a[7] = (short)f2bf(v1.w);
#pragma unroll
    for (int ct = 0; ct < 8; ++ct) {
      bf16x8 b = *reinterpret_cast<const bf16x8*>(Wt + (ct * 16 + r) * DD +
                                                  ks * 32 + 8 * g);
      acc[ct] = __builtin_amdgcn_mfma_f32_16x16x32_bf16(a, b, acc[ct], 0, 0, 0);
    }
  }
#pragma unroll
  for (int ct = 0; ct < 8; ++ct) {
    float bv = bias[ct * 16 + r];
#pragma unroll
    for (int r4 = 0; r4 < 4; ++r4) {
      long row = row0 + 4 * g + r4;
      H[row * DD + ct * 16 + r] = f2bf(fmaxf(acc[ct][r4] + bv, 0.f));
    }
  }
}

// ---------------------------------------------------------------------------
// bf16 [R][128] -> [128][R], optional per-row scale (rsinv fold for msg_g)
// ---------------------------------------------------------------------------
__global__ __launch_bounds__(256) void transpose_k(
    const unsigned short* __restrict__ H, unsigned short* __restrict__ HT,
    int R, const float* __restrict__ scale) {
  __shared__ unsigned short lds[64 * 136];
  int tid = threadIdx.x;
  long r0 = (long)blockIdx.x * 64;
#pragma unroll
  for (int q = 0; q < 4; ++q) {
    int idx = q * 2048 + tid * 8;
    int rr = idx >> 7, cc = idx & 127;
    u16x8 v = *reinterpret_cast<const u16x8*>(H + (r0 + rr) * 128 + cc);
    if (scale) {
      float s = scale[r0 + rr];
#pragma unroll
      for (int i = 0; i < 8; ++i) v[i] = f2bf(bf2f(v[i]) * s);
    }
    *(u16x8*)&lds[rr * 136 + cc] = v;
  }
  __syncthreads();
  int e = tid >> 1, half = tid & 1;
#pragma unroll
  for (int q = 0; q < 4; ++q) {
    u16x8 v;
#pragma unroll
    for (int i = 0; i < 8; ++i)
      v[i] = lds[(half * 32 + q * 8 + i) * 136 + e];
    *reinterpret_cast<u16x8*>(HT + (long)e * R + r0 + half * 32 + q * 8) = v;
  }
}

// ---------------------------------------------------------------------------
// msg_s: block = 128 surface rows (4 waves x 32). Streams Ng in 64-col chunks.
// SOFTWARE-PIPELINED: w fragments for chunk c+1 generated (pos MFMA -> exp ->
// cvt_pk+permlane) while chunk c's 16 msg MFMAs drain. Prologue seeds chunk 0.
// ---------------------------------------------------------------------------
__global__ __launch_bounds__(256) void msg_s_k(
    const unsigned short* __restrict__ pos1_g,
    const unsigned short* __restrict__ pos2_s,
    const unsigned short* __restrict__ xg_hT, unsigned short* __restrict__ xs_o,
    float* __restrict__ rsinv) {
  __shared__ __align__(16) unsigned short ldsB[2][128 * 64];
  const int tid = threadIdx.x;
  const int w = tid >> 6, l = tid & 63;
  const int ln = l & 31, hi = l >> 5;
  const int b = blockIdx.y;
  const long bNS = (long)b * NS, bNG = (long)b * NG;
  const long row0 = (long)blockIdx.x * 128 + w * 32;
  const long BNG = (long)BB * NG;
  const int NCH = NG / 64;

  const bf16x8 bP = *reinterpret_cast<const bf16x8*>(
      pos2_s + (bNS + row0 + ln) * 16 + 8 * hi);

  const f32x16 zz = {0.f, 0.f, 0.f, 0.f, 0.f, 0.f, 0.f, 0.f,
                     0.f, 0.f, 0.f, 0.f, 0.f, 0.f, 0.f, 0.f};
  f32x16 acc[4] = {zz, zz, zz, zz};
  float rs0 = 0.f, rs1 = 0.f, rs2 = 0.f, rs3 = 0.f;

  const int tf = tid >> 3;
  const int tsp = tid & 7;
  const unsigned short* p0 = xg_hT + (long)tf * BNG + bNG + (tsp ^ (tf & 7)) * 8;
  const unsigned short* p1 = p0 + (long)32 * BNG;
  const unsigned short* p2 = p0 + (long)64 * BNG;
  const unsigned short* p3 = p0 + (long)96 * BNG;
  const unsigned short* pp = pos1_g + (bNG + ln) * 16 + 8 * hi;

  u16x8 stA[4];
  stA[0] = *reinterpret_cast<const u16x8*>(p0);
  stA[1] = *reinterpret_cast<const u16x8*>(p1);
  stA[2] = *reinterpret_cast<const u16x8*>(p2);
  stA[3] = *reinterpret_cast<const u16x8*>(p3);
#pragma unroll
  for (int q = 0; q < 4; ++q)
    *(u16x8*)&ldsB[0][(q * 32 + tf) * 64 + tsp * 8] = stA[q];
  stA[0] = *reinterpret_cast<const u16x8*>(p0 + 64);
  stA[1] = *reinterpret_cast<const u16x8*>(p1 + 64);
  stA[2] = *reinterpret_cast<const u16x8*>(p2 + 64);
  stA[3] = *reinterpret_cast<const u16x8*>(p3 + 64);
  p0 += 128; p1 += 128; p2 += 128; p3 += 128;

  // prologue: w fragments for chunk 0
  bf16x8 frC0, frC1, frC2, frC3;
  {
    bf16x8 a0 = *reinterpret_cast<const bf16x8*>(pp);
    f32x16 S = __builtin_amdgcn_mfma_f32_32x32x16_bf16(a0, bP, zz, 0, 0, 0);
    float ex[16];
#pragma unroll
    for (int r = 0; r < 16; ++r) ex[r] = EXP2(S[r] * C2F);
#pragma unroll
    for (int r = 0; r < 4; ++r) {
      rs0 += ex[r]; rs1 += ex[r + 4]; rs2 += ex[r + 8]; rs3 += ex[r + 12];
    }
    PACK_SWAP(ex[0], ex[1], ex[2], ex[3], ex[4], ex[5], ex[6], ex[7], frC0);
    PACK_SWAP(ex[8], ex[9], ex[10], ex[11], ex[12], ex[13], ex[14], ex[15],
              frC1);
    bf16x8 a1 = *reinterpret_cast<const bf16x8*>(pp + 32 * 16);
    S = __builtin_amdgcn_mfma_f32_32x32x16_bf16(a1, bP, zz, 0, 0, 0);
#pragma unroll
    for (int r = 0; r < 16; ++r) ex[r] = EXP2(S[r] * C2F);
#pragma unroll
    for (int r = 0; r < 4; ++r) {
      rs0 += ex[r]; rs1 += ex[r + 4]; rs2 += ex[r + 8]; rs3 += ex[r + 12];
    }
    PACK_SWAP(ex[0], ex[1], ex[2], ex[3], ex[4], ex[5], ex[6], ex[7], frC2);
    PACK_SWAP(ex[8], ex[9], ex[10], ex[11], ex[12], ex[13], ex[14], ex[15],
              frC3);
  }
  __syncthreads();

#pragma unroll 1
  for (int c = 0; c < NCH; ++c) {
    const int buf = c & 1;
    const bool haveN = (c + 1 < NCH);
    bf16x8 frN0, frN1, frN2, frN3;
    f32x16 S;
    if (haveN) {
      bf16x8 a0 =
          *reinterpret_cast<const bf16x8*>(pp + (long)(c + 1) * 1024);
      S = __builtin_amdgcn_mfma_f32_32x32x16_bf16(a0, bP, zz, 0, 0, 0);
    }
#pragma unroll
    for (int kt = 0; kt < 2; ++kt) {
      const bf16x8 fA = kt ? frC1 : frC0;
      const int spr = ((kt * 2 + hi) ^ (ln & 7)) * 8;
#pragma unroll
      for (int nt = 0; nt < 4; ++nt) {
        const bf16x8 bm = *reinterpret_cast<const bf16x8*>(
            &ldsB[buf][(nt * 32 + ln) * 64 + spr]);
        acc[nt] =
            __builtin_amdgcn_mfma_f32_32x32x16_bf16(fA, bm, acc[nt], 0, 0, 0);
      }
    }
    if (haveN) {
      float ex[16];
#pragma unroll
      for (int r = 0; r < 16; ++r) ex[r] = EXP2(S[r] * C2F);
#pragma unroll
      for (int r = 0; r < 4; ++r) {
        rs0 += ex[r]; rs1 += ex[r + 4]; rs2 += ex[r + 8]; rs3 += ex[r + 12];
      }
      PACK_SWAP(ex[0], ex[1], ex[2], ex[3], ex[4], ex[5], ex[6], ex[7], frN0);
      PACK_SWAP(ex[8], ex[9], ex[10], ex[11], ex[12], ex[13], ex[14], ex[15],
                frN1);
      bf16x8 a1 = *reinterpret_cast<const bf16x8*>(pp + (long)(c + 1) * 1024 +
                                                   32 * 16);
      S = __builtin_amdgcn_mfma_f32_32x32x16_bf16(a1, bP, zz, 0, 0, 0);
    }
#pragma unroll
    for (int kt = 2; kt < 4; ++kt) {
      const bf16x8 fA = (kt == 2) ? frC2 : frC3;
      const int spr = ((kt * 2 + hi) ^ (ln & 7)) * 8;
#pragma unroll
      for (int nt = 0; nt < 4; ++nt) {
        const bf16x8 bm = *reinterpret_cast<const bf16x8*>(
            &ldsB[buf][(nt * 32 + ln) * 64 + spr]);
        acc[nt] =
            __builtin_amdgcn_mfma_f32_32x32x16_bf16(fA, bm, acc[nt], 0, 0, 0);
      }
    }
    if (haveN) {
      float ex[16];
#pragma unroll
      for (int r = 0; r < 16; ++r) ex[r] = EXP2(S[r] * C2F);
#pragma unroll
      for (int r = 0; r < 4; ++r) {
        rs0 += ex[r]; rs1 += ex[r + 4]; rs2 += ex[r + 8]; rs3 += ex[r + 12];
      }
      PACK_SWAP(ex[0], ex[1], ex[2], ex[3], ex[4], ex[5], ex[6], ex[7], frN2);
      PACK_SWAP(ex[8], ex[9], ex[10], ex[11], ex[12], ex[13], ex[14], ex[15],
                frN3);
#pragma unroll
      for (int q = 0; q < 4; ++q)
        *(u16x8*)&ldsB[buf ^ 1][(q * 32 + tf) * 64 + tsp * 8] = stA[q];
      frC0 = frN0; frC1 = frN1; frC2 = frN2; frC3 = frN3;
    }
    if (c + 2 < NCH) {
      stA[0] = *reinterpret_cast<const u16x8*>(p0);
      stA[1] = *reinterpret_cast<const u16x8*>(p1);
      stA[2] = *reinterpret_cast<const u16x8*>(p2);
      stA[3] = *reinterpret_cast<const u16x8*>(p3);
      p0 += 64; p1 += 64; p2 += 64; p3 += 64;
    }
    __syncthreads();
  }

  float rtot = (rs0 + rs1) + (rs2 + rs3);
  rtot += __shfl_xor(rtot, 32, 64);
  float denom = rtot + 1e-8f;
  float rsi = 1.f / denom;
  if (hi == 0) rsinv[bNS + row0 + ln] = rsi;
#pragma unroll
  for (int r = 0; r < 16; ++r) {
    const int crow = (r & 3) + 8 * (r >> 2) + 4 * hi;
    float rsib = __shfl(rsi, crow, 64);
    long rowg = bNS + row0 + crow;
#pragma unroll
    for (int nt = 0; nt < 4; ++nt)
      xs_o[rowg * DD + nt * 32 + ln] = f2bf(acc[nt][r] * rsib);
  }
}

// ---------------------------------------------------------------------------
// msg_g: block = 128 graph rows (4 waves x 32). Streams its 1/SPLITG of Ns.
// Same pipeline as msg_s; xs_hT pre-scaled by rsinv; no rowsum.
// ---------------------------------------------------------------------------
__global__ __launch_bounds__(256) void msg_g_k(
    const unsigned short* __restrict__ pos1_s,
    const unsigned short* __restrict__ pos2_g,
    const unsigned short* __restrict__ xs_hT, unsigned short* __restrict__ part) {
  __shared__ __align__(16) unsigned short ldsB[2][128 * 64];
  const int tid = threadIdx.x;
  const int w = tid >> 6, l = tid & 63;
  const int ln = l & 31, hi = l >> 5;
  const int b = blockIdx.y, spz = blockIdx.z;
  const long bNS = (long)b * NS, bNG = (long)b * NG;
  const long nbeg = (long)spz * (NS / SPLITG);
  const long row0 = (long)blockIdx.x * 128 + w * 32;
  const long BNS = (long)BB * NS;
  const int NCH = (NS / SPLITG) / 64;

  const bf16x8 bP = *reinterpret_cast<const bf16x8*>(
      pos2_g + (bNG + row0 + ln) * 16 + 8 * hi);

  const f32x16 zz = {0.f, 0.f, 0.f, 0.f, 0.f, 0.f, 0.f, 0.f,
                     0.f, 0.f, 0.f, 0.f, 0.f, 0.f, 0.f, 0.f};
  f32x16 acc[4] = {zz, zz, zz, zz};

  const int tf = tid >> 3;
  const int tsp = tid & 7;
  const unsigned short* p0 = xs_hT + (long)tf * BNS + bNS + nbeg +
                             (tsp ^ (tf & 7)) * 8;
  const unsigned short* p1 = p0 + (long)32 * BNS;
  const unsigned short* p2 = p0 + (long)64 * BNS;
  const unsigned short* p3 = p0 + (long)96 * BNS;
  const unsigned short* pp = pos1_s + (bNS + nbeg + ln) * 16 + 8 * hi;

  u16x8 stA[4];
  stA[0] = *reinterpret_cast<const u16x8*>(p0);
  stA[1] = *reinterpret_cast<const u16x8*>(p1);
  stA[2] = *reinterpret_cast<const u16x8*>(p2);
  stA[3] = *reinterpret_cast<const u16x8*>(p3);
#pragma unroll
  for (int q = 0; q < 4; ++q)
    *(u16x8*)&ldsB[0][(q * 32 + tf) * 64 + tsp * 8] = stA[q];
  stA[0] = *reinterpret_cast<const u16x8*>(p0 + 64);
  stA[1] = *reinterpret_cast<const u16x8*>(p1 + 64);
  stA[2] = *reinterpret_cast<const u16x8*>(p2 + 64);
  stA[3] = *reinterpret_cast<const u16x8*>(p3 + 64);
  p0 += 128; p1 += 128; p2 += 128; p3 += 128;

  bf16x8 frC0, frC1, frC2, frC3;
  {
    bf16x8 a0 = *reinterpret_cast<const bf16x8*>(pp);
    f32x16 S = __builtin_amdgcn_mfma_f32_32x32x16_bf16(a0, bP, zz, 0, 0, 0);
    float ex[16];
#pragma unroll
    for (int r = 0; r < 16; ++r) ex[r] = EXP2(S[r] * C2F);
    PACK_SWAP(ex[0], ex[1], ex[2], ex[3], ex[4], ex[5], ex[6], ex[7], frC0);
    PACK_SWAP(ex[8], ex[9], ex[10], ex[11], ex[12], ex[13], ex[14], ex[15],
              frC1);
    bf16x8 a1 = *reinterpret_cast<const bf16x8*>(pp + 32 * 16);
    S = __builtin_amdgcn_mfma_f32_32x32x16_bf16(a1, bP, zz, 0, 0, 0);
#pragma unroll
    for (int r = 0; r < 16; ++r) ex[r] = EXP2(S[r] * C2F);
    PACK_SWAP(ex[0], ex[1], ex[2], ex[3], ex[4], ex[5], ex[6], ex[7], frC2);
    PACK_SWAP(ex[8], ex[9], ex[10], ex[11], ex[12], ex[13], ex[14], ex[15],
              frC3);
  }
  __syncthreads();

#pragma unroll 1
  for (int c = 0; c < NCH; ++c) {
    const int buf = c & 1;
    const bool haveN = (c + 1 < NCH);
    bf16x8 frN0, frN1, frN2, frN3;
    f32x16 S;
    if (haveN) {
      bf16x8 a0 =
          *reinterpret_cast<const bf16x8*>(pp + (long)(c + 1) * 1024);
      S = __builtin_amdgcn_mfma_f32_32x32x16_bf16(a0, bP, zz, 0, 0, 0);
    }
#pragma unroll
    for (int kt = 0; kt < 2; ++kt) {
      const bf16x8 fA = kt ? frC1 : frC0;
      const int spr = ((kt * 2 + hi) ^ (ln & 7)) * 8;
#pragma unroll
      for (int nt = 0; nt < 4; ++nt) {
        const bf16x8 bm = *reinterpret_cast<const bf16x8*>(
            &ldsB[buf][(nt * 32 + ln) * 64 + spr]);
        acc[nt] =
            __builtin_amdgcn_mfma_f32_32x32x16_bf16(fA, bm, acc[nt], 0, 0, 0);
      }
    }
    if (haveN) {
      float ex[16];
#pragma unroll
      for (int r = 0; r < 16; ++r) ex[r] = EXP2(S[r] * C2F);
      PACK_SWAP(ex[0], ex[1], ex[2], ex[3], ex[4], ex[5], ex[6], ex[7], frN0);
      PACK_SWAP(ex[8], ex[9], ex[10], ex[11], ex[12], ex[13], ex[14], ex[15],
                frN1);
      bf16x8 a1 = *reinterpret_cast<const bf16x8*>(pp + (long)(c + 1) * 1024 +
                                                   32 * 16);
      S = __builtin_amdgcn_mfma_f32_32x32x16_bf16(a1, bP, zz, 0, 0, 0);
    }
#pragma unroll
    for (int kt = 2; kt < 4; ++kt) {
      const bf16x8 fA = (kt == 2) ? frC2 : frC3;
      const int spr = ((kt * 2 + hi) ^ (ln & 7)) * 8;
#pragma unroll
      for (int nt = 0; nt < 4; ++nt) {
        const bf16x8 bm = *reinterpret_cast<const bf16x8*>(
            &ldsB[buf][(nt * 32 + ln) * 64 + spr]);
        acc[nt] =
            __builtin_amdgcn_mfma_f32_32x32x16_bf16(fA, bm, acc[nt], 0, 0, 0);
      }
    }
    if (haveN) {
      float ex[16];
#pragma unroll
      for (int r = 0; r < 16; ++r) ex[r] = EXP2(S[r] * C2F);
      PACK_SWAP(ex[0], ex[1], ex[2], ex[3], ex[4], ex[5], ex[6], ex[7], frN2);
      PACK_SWAP(ex[8], ex[9], ex[10], ex[11], ex[12], ex[13], ex[14], ex[15],
                frN3);
#pragma unroll
      for (int q = 0; q < 4; ++q)
        *(u16x8*)&ldsB[buf ^ 1][(q * 32 + tf) * 64 + tsp * 8] = stA[q];
      frC0 = frN0; frC1 = frN1; frC2 = frN2; frC3 = frN3;
    }
    if (c + 2 < NCH) {
      stA[0] = *reinterpret_cast<const u16x8*>(p0);
      stA[1] = *reinterpret_cast<const u16x8*>(p1);
      stA[2] = *reinterpret_cast<const u16x8*>(p2);
      stA[3] = *reinterpret_cast<const u16x8*>(p3);
      p0 += 64; p1 += 64; p2 += 64; p3 += 64;
    }
    __syncthreads();
  }

  const long pbase = (long)spz * BB * NG;
#pragma unroll
  for (int r = 0; r < 16; ++r) {
    const int crow = (r & 3) + 8 * (r >> 2) + 4 * hi;
    long rowg = pbase + bNG + row0 + crow;
#pragma unroll
    for (int nt = 0; nt < 4; ++nt)
      part[rowg * DD + nt * 32 + ln] = f2bf(acc[nt][r]);
  }
}

__global__ __launch_bounds__(256) void reduce_k(
    const unsigned short* __restrict__ part, unsigned short* __restrict__ xg_o) {
  long i = ((long)blockIdx.x * 256 + threadIdx.x) * 8;
  const long S = (long)BB * NG * DD;
  float a[8];
#pragma unroll
  for (int k = 0; k < 8; ++k) a[k] = 0.f;
#pragma unroll
  for (int s = 0; s < SPLITG; ++s) {
    u16x8 v = *reinterpret_cast<const u16x8*>(part + s * S + i);
#pragma unroll
    for (int k = 0; k < 8; ++k) a[k] += bf2f(v[k]);
  }
  u16x8 o;
#pragma unroll
  for (int k = 0; k < 8; ++k) o[k] = f2bf(a[k]);
  *reinterpret_cast<u16x8*>(xg_o + i) = o;
}

// ---------------------------------------------------------------------------
// post GEMM: out = relu([Ha|Hb] @ W + b), K=256, f32 output.
// ---------------------------------------------------------------------------
__global__ __launch_bounds__(256) void post_mfma_k(
    const unsigned short* __restrict__ Ha, const unsigned short* __restrict__ Hb,
    const unsigned short* __restrict__ Wt, const float* __restrict__ bias,
    float* __restrict__ out, int shift, int mask, int off) {
  int tid = threadIdx.x, l = tid & 63, w = tid >> 6;
  int g = l >> 4, r = l & 15;
  long row0 = (long)blockIdx.x * 64 + w * 16;
  const unsigned short* ha = Ha + (row0 + r) * DD;
  const unsigned short* hb = Hb + (row0 + r) * DD;
  f32x4 z4 = {0.f, 0.f, 0.f, 0.f};
  f32x4 acc[8];
#pragma unroll
  for (int i = 0; i < 8; ++i) acc[i] = z4;
#pragma unroll
  for (int ks = 0; ks < 8; ++ks) {
    const unsigned short* src = (ks < 4) ? (ha + ks * 32) : (hb + (ks - 4) * 32);
    bf16x8 a = *reinterpret_cast<const bf16x8*>(src + 8 * g);
#pragma unroll
    for (int ct = 0; ct < 8; ++ct) {
      bf16x8 b = *reinterpret_cast<const bf16x8*>(Wt + (ct * 16 + r) * 256 +
                                                  ks * 32 + 8 * g);
      acc[ct] = __builtin_amdgcn_mfma_f32_16x16x32_bf16(a, b, acc[ct], 0, 0, 0);
    }
  }
#pragma unroll
  for (int ct = 0; ct < 8; ++ct) {
    float bv = bias[ct * 16 + r];
#pragma unroll
    for (int r4 = 0; r4 < 4; ++r4) {
      long rowg = row0 + 4 * g + r4;
      long bb = rowg >> shift;
      long n = rowg & mask;
      out[(bb * (NS + NG) + off + n) * DD + ct * 16 + r] =
          fmaxf(acc[ct][r4] + bv, 0.f);
    }
  }
}

// ---------------------------------------------------------------------------
extern "C" void kernel_launch(void* const* d_in, const int* in_sizes, int n_in,
                              void* d_out, int out_size, void* d_ws,
                              size_t ws_size, hipStream_t stream) {
  const float* xs = (const float*)d_in[0];
  const float* xg = (const float*)d_in[1];
  const float* vs = (const float*)d_in[2];
  const float* vg = (const float*)d_in[3];
  const float* Ws_pre = (const float*)d_in[4];
  const float* bs_pre = (const float*)d_in[5];
  const float* Wg_pre = (const float*)d_in[6];
  const float* bg_pre = (const float*)d_in[7];
  const float* Ws_post = (const float*)d_in[8];
  const float* bs_post = (const float*)d_in[9];
  const float* Wg_post = (const float*)d_in[10];
  const float* bg_post = (const float*)d_in[11];
  float* out = (float*)d_out;

  char* p = (char*)d_ws;
  unsigned short* pos1_s = (unsigned short*)p; p += (size_t)BB * NS * 16 * 2;
  unsigned short* pos2_s = (unsigned short*)p; p += (size_t)BB * NS * 16 * 2;
  unsigned short* pos1_g = (unsigned short*)p; p += (size_t)BB * NG * 16 * 2;
  unsigned short* pos2_g = (unsigned short*)p; p += (size_t)BB * NG * 16 * 2;
  unsigned short* WtS_pre = (unsigned short*)p; p += (size_t)128 * 128 * 2;
  unsigned short* WtG_pre = (unsigned short*)p; p += (size_t)128 * 128 * 2;
  unsigned short* WtS_post = (unsigned short*)p; p += (size_t)128 * 256 * 2;
  unsigned short* WtG_post = (unsigned short*)p; p += (size_t)128 * 256 * 2;
  unsigned short* xg_h = (unsigned short*)p; p += (size_t)BB * NG * DD * 2;
  unsigned short* xg_hT = (unsigned short*)p; p += (size_t)BB * NG * DD * 2;
  unsigned short* xs_hT = (unsigned short*)p; p += (size_t)BB * NS * DD * 2;
  unsigned short* xg_o = (unsigned short*)p; p += (size_t)BB * NG * DD * 2;
  float* rsinv = (float*)p; p += (size_t)BB * NS * 4;
  // region R: [xs_h | xs_o] — dead after post_s — reused as msg_g partials
  unsigned short* xs_h = (unsigned short*)p;
  unsigned short* xs_o = xs_h + (size_t)BB * NS * DD;
  unsigned short* part_g = xs_h;  // SPLITG * BB*NG*DD = 2 * BB*NS*DD exactly
  p += (size_t)2 * BB * NS * DD * 2;

  prep_k<<<(BB * (NS + NG)) / 256 + 98304 / 256, 256, 0, stream>>>(
      vs, vg, Ws_pre, Wg_pre, Ws_post, Wg_post, pos1_s, pos2_s, pos1_g,
      pos2_g, WtS_pre, WtG_pre, WtS_post, WtG_post);
  pre_mfma_k<<<(BB * NS + BB * NG) / 64, 256, 0, stream>>>(
      xs, xg, WtS_pre, WtG_pre, bs_pre, bg_pre, xs_h, xg_h);
  transpose_k<<<BB * NG / 64, 256, 0, stream>>>(xg_h, xg_hT, BB * NG, nullptr);
  msg_s_k<<<dim3(NS / 128, BB), 256, 0, stream>>>(pos1_g, pos2_s, xg_hT, xs_o,
                                                  rsinv);
  transpose_k<<<BB * NS / 64, 256, 0, stream>>>(xs_h, xs_hT, BB * NS, rsinv);
  post_mfma_k<<<BB * NS / 64, 256, 0, stream>>>(xs_h, xs_o, WtS_post, bs_post,
                                                out, 14, NS - 1, 0);
  msg_g_k<<<dim3(NG / 128, BB, SPLITG), 256, 0, stream>>>(pos1_s, pos2_g,
                                                          xs_hT, part_g);
  reduce_k<<<(BB * NG * DD) / 8 / 256, 256, 0, stream>>>(part_g, xg_o);
  post_mfma_k<<<BB * NG / 64, 256, 0, stream>>>(xg_h, xg_o, WtG_post, bg_post,
                                                out, 11, NG - 1, NS);
}

// Round 10
// 204.774 us; speedup vs baseline: 1.0166x; 1.0166x over previous
//
#include <hip/hip_runtime.h>
#include <hip/hip_bf16.h>

#define BB 4
#define NS 16384
#define NG 2048
#define DD 128
#define SPLITG 16
#define C2F (-0.23083120f)  // -log2(e)/sigma^2

typedef short bf16x8 __attribute__((ext_vector_type(8)));
typedef unsigned short u16x8 __attribute__((ext_vector_type(8)));
typedef float f32x4 __attribute__((ext_vector_type(4)));
typedef float f32x16 __attribute__((ext_vector_type(16)));
typedef int i32x4 __attribute__((ext_vector_type(4)));

// exp2: builtin (compiler-known hazards) or libcall. NEVER naked asm.
#if __has_builtin(__builtin_amdgcn_exp2f)
#define EXP2(x) __builtin_amdgcn_exp2f(x)
#else
#define EXP2(x) exp2f(x)
#endif

__device__ __forceinline__ unsigned short f2bf(float x) {
  unsigned int u = __builtin_bit_cast(unsigned int, x);
  u += 0x7FFFu + ((u >> 16) & 1u);
  return (unsigned short)(u >> 16);
}
__device__ __forceinline__ float bf2f(unsigned short h) {
  unsigned int u = ((unsigned int)h) << 16;
  return __builtin_bit_cast(float, u);
}

// pack 8 f32 -> bf16x8 A-fragment via cvt_pk + permlane32_swap (T12 recipe).
// HARDENED single asm block (earlyclobbers + s_nop guards) — r8-verified.
#define PACK_SWAP(e0, e1, e2, e3, e4, e5, e6, e7, OUT)                        \
  {                                                                           \
    unsigned pq0, pq1, pq2, pq3;                                              \
    asm("v_cvt_pk_bf16_f32 %0, %4, %5\n\t"                                    \
        "v_cvt_pk_bf16_f32 %1, %6, %7\n\t"                                    \
        "v_cvt_pk_bf16_f32 %2, %8, %9\n\t"                                    \
        "v_cvt_pk_bf16_f32 %3, %10, %11\n\t"                                  \
        "s_nop 1\n\t"                                                         \
        "v_permlane32_swap_b32 %0, %2\n\t"                                    \
        "v_permlane32_swap_b32 %1, %3\n\t"                                    \
        "s_nop 1"                                                             \
        : "=&v"(pq0), "=&v"(pq1), "=&v"(pq2), "=&v"(pq3)                      \
        : "v"(e0), "v"(e1), "v"(e2), "v"(e3), "v"(e4), "v"(e5), "v"(e6),      \
          "v"(e7));                                                           \
    i32x4 tmp_ = {(int)pq0, (int)pq1, (int)pq2, (int)pq3};                    \
    OUT = __builtin_bit_cast(bf16x8, tmp_);                                   \
  }

// ---------------------------------------------------------------------------
// prep: node pos encodings (UNSCALED verified form: dot(pos1,pos2)=d2, hi/lo
// split) + weight transposes, fused into one launch.
// ---------------------------------------------------------------------------
__device__ __forceinline__ void posprep1(const float* __restrict__ v, int i,
                                         unsigned short* __restrict__ pos1,
                                         unsigned short* __restrict__ pos2) {
  float x = v[i * 3 + 0], y = v[i * 3 + 1], z = v[i * 3 + 2];
  unsigned short hx = f2bf(x), hy = f2bf(y), hz = f2bf(z);
  float fx = bf2f(hx), fy = bf2f(hy), fz = bf2f(hz);
  unsigned short lx = f2bf(x - fx), ly = f2bf(y - fy), lz = f2bf(z - fz);
  float n = x * x + y * y + z * z;
  unsigned short nh = f2bf(n);
  unsigned short nl = f2bf(n - bf2f(nh));
  unsigned short m2hx = f2bf(-2.f * fx), m2hy = f2bf(-2.f * fy),
                 m2hz = f2bf(-2.f * fz);
  unsigned short m2lx = f2bf(-2.f * bf2f(lx)), m2ly = f2bf(-2.f * bf2f(ly)),
                 m2lz = f2bf(-2.f * bf2f(lz));
  const unsigned short one = 0x3F80;
  u16x8 a0 = {m2hx, m2hy, m2hz, m2lx, m2ly, m2lz, m2hx, m2hy};
  u16x8 a1 = {m2hz, m2lx, m2ly, m2lz, nh, nl, one, one};
  u16x8 b0 = {hx, hy, hz, hx, hy, hz, lx, ly};
  u16x8 b1 = {lz, lx, ly, lz, one, one, nh, nl};
  *(u16x8*)(pos1 + (long)i * 16) = a0;
  *(u16x8*)(pos1 + (long)i * 16 + 8) = a1;
  *(u16x8*)(pos2 + (long)i * 16) = b0;
  *(u16x8*)(pos2 + (long)i * 16 + 8) = b1;
}

__global__ __launch_bounds__(256) void prep_k(
    const float* __restrict__ vs, const float* __restrict__ vg,
    const float* __restrict__ Ws_pre, const float* __restrict__ Wg_pre,
    const float* __restrict__ Ws_post, const float* __restrict__ Wg_post,
    unsigned short* __restrict__ pos1_s, unsigned short* __restrict__ pos2_s,
    unsigned short* __restrict__ pos1_g, unsigned short* __restrict__ pos2_g,
    unsigned short* __restrict__ WtS_pre, unsigned short* __restrict__ WtG_pre,
    unsigned short* __restrict__ WtS_post,
    unsigned short* __restrict__ WtG_post) {
  const int NODEBLK = (BB * (NS + NG)) / 256;  // 288
  int bid = blockIdx.x, tid = threadIdx.x;
  if (bid < NODEBLK) {
    int i = bid * 256 + tid;
    if (i < BB * NS)
      posprep1(vs, i, pos1_s, pos2_s);
    else
      posprep1(vg, i - BB * NS, pos1_g, pos2_g);
  } else {
    int k2 = (bid - NODEBLK) * 256 + tid;
    const float* W;
    unsigned short* Wt;
    int kshift, loc;
    if (k2 < 16384) { W = Ws_pre; Wt = WtS_pre; kshift = 7; loc = k2; }
    else if (k2 < 32768) { W = Wg_pre; Wt = WtG_pre; kshift = 7; loc = k2 - 16384; }
    else if (k2 < 65536) { W = Ws_post; Wt = WtS_post; kshift = 8; loc = k2 - 32768; }
    else { W = Wg_post; Wt = WtG_post; kshift = 8; loc = k2 - 65536; }
    int K = 1 << kshift;
    int e = loc >> kshift, k = loc & (K - 1);
    Wt[(long)e * K + k] = f2bf(W[(long)k * 128 + e]);
  }
}

// ---------------------------------------------------------------------------
// pre GEMM (surface + graph fused): H = relu(X @ W + b), K=128.
// ---------------------------------------------------------------------------
__global__ __launch_bounds__(256) void pre_mfma_k(
    const float* __restrict__ xs, const float* __restrict__ xg,
    const unsigned short* __restrict__ WtS,
    const unsigned short* __restrict__ WtG, const float* __restrict__ bs,
    const float* __restrict__ bg, unsigned short* __restrict__ xs_h,
    unsigned short* __restrict__ xg_h) {
  long r0 = (long)blockIdx.x * 64;
  const float* X;
  const unsigned short* Wt;
  const float* bias;
  unsigned short* H;
  long row0;
  if (r0 < (long)BB * NS) {
    X = xs; Wt = WtS; bias = bs; H = xs_h; row0 = r0;
  } else {
    X = xg; Wt = WtG; bias = bg; H = xg_h; row0 = r0 - (long)BB * NS;
  }
  int tid = threadIdx.x, l = tid & 63, w = tid >> 6;
  int g = l >> 4, r = l & 15;
  row0 += w * 16;
  const float* xrow = X + (row0 + r) * DD;
  f32x4 z4 = {0.f, 0.f, 0.f, 0.f};
  f32x4 acc[8];
#pragma unroll
  for (int i = 0; i < 8; ++i) acc[i] = z4;
#pragma unroll
  for (int ks = 0; ks < 4; ++ks) {
    float4 v0 = *(const float4*)(xrow + ks * 32 + 8 * g);
    float4 v1 = *(const float4*)(xrow + ks * 32 + 8 * g + 4);
    bf16x8 a;
    a[0] = (short)f2bf(v0.x); a[1] = (short)f2bf(v0.y);
    a[2] = (short)f2bf(v0.z); a[3] = (short)f2bf(v0.w);
    a[4] = (short)f2bf(v1.x); a[5] = (short)f2bf(v1.y);
    a[6] = (short)f2bf(v1.z); a[7] = (short)f2bf(v1.w);
#pragma unroll
    for (int ct = 0; ct < 8; ++ct) {
      bf16x8 b = *reinterpret_cast<const bf16x8*>(Wt + (ct * 16 + r) * DD +
                                                  ks * 32 + 8 * g);
      acc[ct] = __builtin_amdgcn_mfma_f32_16x16x32_bf16(a, b, acc[ct], 0, 0, 0);
    }
  }
#pragma unroll
  for (int ct = 0; ct < 8; ++ct) {
    float bv = bias[ct * 16 + r];
#pragma unroll
    for (int r4 = 0; r4 < 4; ++r4) {
      long row = row0 + 4 * g + r4;
      H[row * DD + ct * 16 + r] = f2bf(fmaxf(acc[ct][r4] + bv, 0.f));
    }
  }
}

// ---------------------------------------------------------------------------
// bf16 [R][128] -> [128][R], optional per-row scale (rsinv fold for msg_g)
// ---------------------------------------------------------------------------
__global__ __launch_bounds__(256) void transpose_k(
    const unsigned short* __restrict__ H, unsigned short* __restrict__ HT,
    int R, const float* __restrict__ scale) {
  __shared__ unsigned short lds[64 * 136];
  int tid = threadIdx.x;
  long r0 = (long)blockIdx.x * 64;
#pragma unroll
  for (int q = 0; q < 4; ++q) {
    int idx = q * 2048 + tid * 8;
    int rr = idx >> 7, cc = idx & 127;
    u16x8 v = *reinterpret_cast<const u16x8*>(H + (r0 + rr) * 128 + cc);
    if (scale) {
      float s = scale[r0 + rr];
#pragma unroll
      for (int i = 0; i < 8; ++i) v[i] = f2bf(bf2f(v[i]) * s);
    }
    *(u16x8*)&lds[rr * 136 + cc] = v;
  }
  __syncthreads();
  int e = tid >> 1, half = tid & 1;
#pragma unroll
  for (int q = 0; q < 4; ++q) {
    u16x8 v;
#pragma unroll
    for (int i = 0; i < 8; ++i)
      v[i] = lds[(half * 32 + q * 8 + i) * 136 + e];
    *reinterpret_cast<u16x8*>(HT + (long)e * R + r0 + half * 32 + q * 8) = v;
  }
}

// ---------------------------------------------------------------------------
// msg_s: block = 128 surface rows (4 waves x 32). Streams Ng in 64-col chunks.
// Swapped pos MFMA (32x32x16) -> d2 in regs -> v_exp(d2*C2) -> cvt_pk+permlane
// -> msg MFMA A-frags. Features [128][64] in LDS, slot^f&7 swizzle, dbuf.
// r4-verified structure; only PACK_SWAP macro hardened.
// ---------------------------------------------------------------------------
__global__ __launch_bounds__(256) void msg_s_k(
    const unsigned short* __restrict__ pos1_g,
    const unsigned short* __restrict__ pos2_s,
    const unsigned short* __restrict__ xg_hT, unsigned short* __restrict__ xs_o,
    float* __restrict__ rsinv) {
  __shared__ __align__(16) unsigned short ldsB[2][128 * 64];
  const int tid = threadIdx.x;
  const int w = tid >> 6, l = tid & 63;
  const int ln = l & 31, hi = l >> 5;
  const int b = blockIdx.y;
  const long bNS = (long)b * NS, bNG = (long)b * NG;
  const long row0 = (long)blockIdx.x * 128 + w * 32;
  const long BNG = (long)BB * NG;
  const int NCH = NG / 64;

  const bf16x8 bP = *reinterpret_cast<const bf16x8*>(
      pos2_s + (bNS + row0 + ln) * 16 + 8 * hi);

  const f32x16 zz = {0.f, 0.f, 0.f, 0.f, 0.f, 0.f, 0.f, 0.f,
                     0.f, 0.f, 0.f, 0.f, 0.f, 0.f, 0.f, 0.f};
  f32x16 acc[4] = {zz, zz, zz, zz};
  float rs0 = 0.f, rs1 = 0.f, rs2 = 0.f, rs3 = 0.f;

  const int tf = tid >> 3;
  const int tsp = tid & 7;
  const unsigned short* p0 = xg_hT + (long)tf * BNG + bNG + (tsp ^ (tf & 7)) * 8;
  const unsigned short* p1 = p0 + (long)32 * BNG;
  const unsigned short* p2 = p0 + (long)64 * BNG;
  const unsigned short* p3 = p0 + (long)96 * BNG;
  const unsigned short* pp = pos1_g + (bNG + ln) * 16 + 8 * hi;

  u16x8 stA[4];
  bf16x8 pA0, pA1, pA0n, pA1n;
  stA[0] = *reinterpret_cast<const u16x8*>(p0);
  stA[1] = *reinterpret_cast<const u16x8*>(p1);
  stA[2] = *reinterpret_cast<const u16x8*>(p2);
  stA[3] = *reinterpret_cast<const u16x8*>(p3);
#pragma unroll
  for (int q = 0; q < 4; ++q)
    *(u16x8*)&ldsB[0][(q * 32 + tf) * 64 + tsp * 8] = stA[q];
  stA[0] = *reinterpret_cast<const u16x8*>(p0 + 64);
  stA[1] = *reinterpret_cast<const u16x8*>(p1 + 64);
  stA[2] = *reinterpret_cast<const u16x8*>(p2 + 64);
  stA[3] = *reinterpret_cast<const u16x8*>(p3 + 64);
  p0 += 128; p1 += 128; p2 += 128; p3 += 128;
  pA0 = *reinterpret_cast<const bf16x8*>(pp);
  pA1 = *reinterpret_cast<const bf16x8*>(pp + 32 * 16);
  pA0n = *reinterpret_cast<const bf16x8*>(pp + 64 * 16);
  pA1n = *reinterpret_cast<const bf16x8*>(pp + 96 * 16);
  pp += 128 * 16;
  __syncthreads();

#pragma unroll 1
  for (int c = 0; c < NCH; ++c) {
    const int buf = c & 1;
    float ex[2][16];
    bf16x8 fr[2][2];
#pragma unroll
    for (int t2 = 0; t2 < 2; ++t2) {
      f32x16 S = __builtin_amdgcn_mfma_f32_32x32x16_bf16(t2 ? pA1 : pA0, bP,
                                                         zz, 0, 0, 0);
#pragma unroll
      for (int r = 0; r < 16; ++r) ex[t2][r] = EXP2(S[r] * C2F);
      PACK_SWAP(ex[t2][0], ex[t2][1], ex[t2][2], ex[t2][3], ex[t2][4],
                ex[t2][5], ex[t2][6], ex[t2][7], fr[t2][0]);
      PACK_SWAP(ex[t2][8], ex[t2][9], ex[t2][10], ex[t2][11], ex[t2][12],
                ex[t2][13], ex[t2][14], ex[t2][15], fr[t2][1]);
    }
#pragma unroll
    for (int r = 0; r < 4; ++r) {
      rs0 += ex[0][r] + ex[1][r];
      rs1 += ex[0][r + 4] + ex[1][r + 4];
      rs2 += ex[0][r + 8] + ex[1][r + 8];
      rs3 += ex[0][r + 12] + ex[1][r + 12];
    }
#pragma unroll
    for (int t2 = 0; t2 < 2; ++t2) {
#pragma unroll
      for (int kh = 0; kh < 2; ++kh) {
        const int kt = t2 * 2 + kh;
        const int spr = ((kt * 2 + hi) ^ (ln & 7)) * 8;
#pragma unroll
        for (int nt = 0; nt < 4; ++nt) {
          const bf16x8 bm = *reinterpret_cast<const bf16x8*>(
              &ldsB[buf][(nt * 32 + ln) * 64 + spr]);
          acc[nt] = __builtin_amdgcn_mfma_f32_32x32x16_bf16(fr[t2][kh], bm,
                                                            acc[nt], 0, 0, 0);
        }
      }
    }
    if (c + 1 < NCH) {
#pragma unroll
      for (int q = 0; q < 4; ++q)
        *(u16x8*)&ldsB[buf ^ 1][(q * 32 + tf) * 64 + tsp * 8] = stA[q];
    }
    if (c + 2 < NCH) {
      stA[0] = *reinterpret_cast<const u16x8*>(p0);
      stA[1] = *reinterpret_cast<const u16x8*>(p1);
      stA[2] = *reinterpret_cast<const u16x8*>(p2);
      stA[3] = *reinterpret_cast<const u16x8*>(p3);
      p0 += 64; p1 += 64; p2 += 64; p3 += 64;
    }
    pA0 = pA0n;
    pA1 = pA1n;
    if (c + 2 < NCH) {
      pA0n = *reinterpret_cast<const bf16x8*>(pp);
      pA1n = *reinterpret_cast<const bf16x8*>(pp + 32 * 16);
      pp += 64 * 16;
    }
    __syncthreads();
  }

  float rtot = (rs0 + rs1) + (rs2 + rs3);
  rtot += __shfl_xor(rtot, 32, 64);
  float denom = rtot + 1e-8f;
  float rsi = 1.f / denom;
  if (hi == 0) rsinv[bNS + row0 + ln] = rsi;
#pragma unroll
  for (int r = 0; r < 16; ++r) {
    const int crow = (r & 3) + 8 * (r >> 2) + 4 * hi;
    float rsib = __shfl(rsi, crow, 64);
    long rowg = bNS + row0 + crow;
#pragma unroll
    for (int nt = 0; nt < 4; ++nt)
      xs_o[rowg * DD + nt * 32 + ln] = f2bf(acc[nt][r] * rsib);
  }
}

// ---------------------------------------------------------------------------
// msg_g: block = 128 graph rows (4 waves x 32). Streams its 1/SPLITG of Ns.
// xs_hT pre-scaled by rsinv. r4-verified structure; PACK_SWAP hardened.
// ---------------------------------------------------------------------------
__global__ __launch_bounds__(256) void msg_g_k(
    const unsigned short* __restrict__ pos1_s,
    const unsigned short* __restrict__ pos2_g,
    const unsigned short* __restrict__ xs_hT, unsigned short* __restrict__ part) {
  __shared__ __align__(16) unsigned short ldsB[2][128 * 64];
  const int tid = threadIdx.x;
  const int w = tid >> 6, l = tid & 63;
  const int ln = l & 31, hi = l >> 5;
  const int b = blockIdx.y, spz = blockIdx.z;
  const long bNS = (long)b * NS, bNG = (long)b * NG;
  const long nbeg = (long)spz * (NS / SPLITG);
  const long row0 = (long)blockIdx.x * 128 + w * 32;
  const long BNS = (long)BB * NS;
  const int NCH = (NS / SPLITG) / 64;

  const bf16x8 bP = *reinterpret_cast<const bf16x8*>(
      pos2_g + (bNG + row0 + ln) * 16 + 8 * hi);

  const f32x16 zz = {0.f, 0.f, 0.f, 0.f, 0.f, 0.f, 0.f, 0.f,
                     0.f, 0.f, 0.f, 0.f, 0.f, 0.f, 0.f, 0.f};
  f32x16 acc[4] = {zz, zz, zz, zz};

  const int tf = tid >> 3;
  const int tsp = tid & 7;
  const unsigned short* p0 = xs_hT + (long)tf * BNS + bNS + nbeg +
                             (tsp ^ (tf & 7)) * 8;
  const unsigned short* p1 = p0 + (long)32 * BNS;
  const unsigned short* p2 = p0 + (long)64 * BNS;
  const unsigned short* p3 = p0 + (long)96 * BNS;
  const unsigned short* pp = pos1_s + (bNS + nbeg + ln) * 16 + 8 * hi;

  u16x8 stA[4];
  bf16x8 pA0, pA1, pA0n, pA1n;
  stA[0] = *reinterpret_cast<const u16x8*>(p0);
  stA[1] = *reinterpret_cast<const u16x8*>(p1);
  stA[2] = *reinterpret_cast<const u16x8*>(p2);
  stA[3] = *reinterpret_cast<const u16x8*>(p3);
#pragma unroll
  for (int q = 0; q < 4; ++q)
    *(u16x8*)&ldsB[0][(q * 32 + tf) * 64 + tsp * 8] = stA[q];
  stA[0] = *reinterpret_cast<const u16x8*>(p0 + 64);
  stA[1] = *reinterpret_cast<const u16x8*>(p1 + 64);
  stA[2] = *reinterpret_cast<const u16x8*>(p2 + 64);
  stA[3] = *reinterpret_cast<const u16x8*>(p3 + 64);
  p0 += 128; p1 += 128; p2 += 128; p3 += 128;
  pA0 = *reinterpret_cast<const bf16x8*>(pp);
  pA1 = *reinterpret_cast<const bf16x8*>(pp + 32 * 16);
  pA0n = *reinterpret_cast<const bf16x8*>(pp + 64 * 16);
  pA1n = *reinterpret_cast<const bf16x8*>(pp + 96 * 16);
  pp += 128 * 16;
  __syncthreads();

#pragma unroll 1
  for (int c = 0; c < NCH; ++c) {
    const int buf = c & 1;
    float ex[2][16];
    bf16x8 fr[2][2];
#pragma unroll
    for (int t2 = 0; t2 < 2; ++t2) {
      f32x16 S = __builtin_amdgcn_mfma_f32_32x32x16_bf16(t2 ? pA1 : pA0, bP,
                                                         zz, 0, 0, 0);
#pragma unroll
      for (int r = 0; r < 16; ++r) ex[t2][r] = EXP2(S[r] * C2F);
      PACK_SWAP(ex[t2][0], ex[t2][1], ex[t2][2], ex[t2][3], ex[t2][4],
                ex[t2][5], ex[t2][6], ex[t2][7], fr[t2][0]);
      PACK_SWAP(ex[t2][8], ex[t2][9], ex[t2][10], ex[t2][11], ex[t2][12],
                ex[t2][13], ex[t2][14], ex[t2][15], fr[t2][1]);
    }
#pragma unroll
    for (int t2 = 0; t2 < 2; ++t2) {
#pragma unroll
      for (int kh = 0; kh < 2; ++kh) {
        const int kt = t2 * 2 + kh;
        const int spr = ((kt * 2 + hi) ^ (ln & 7)) * 8;
#pragma unroll
        for (int nt = 0; nt < 4; ++nt) {
          const bf16x8 bm = *reinterpret_cast<const bf16x8*>(
              &ldsB[buf][(nt * 32 + ln) * 64 + spr]);
          acc[nt] = __builtin_amdgcn_mfma_f32_32x32x16_bf16(fr[t2][kh], bm,
                                                            acc[nt], 0, 0, 0);
        }
      }
    }
    if (c + 1 < NCH) {
#pragma unroll
      for (int q = 0; q < 4; ++q)
        *(u16x8*)&ldsB[buf ^ 1][(q * 32 + tf) * 64 + tsp * 8] = stA[q];
    }
    if (c + 2 < NCH) {
      stA[0] = *reinterpret_cast<const u16x8*>(p0);
      stA[1] = *reinterpret_cast<const u16x8*>(p1);
      stA[2] = *reinterpret_cast<const u16x8*>(p2);
      stA[3] = *reinterpret_cast<const u16x8*>(p3);
      p0 += 64; p1 += 64; p2 += 64; p3 += 64;
    }
    pA0 = pA0n;
    pA1 = pA1n;
    if (c + 2 < NCH) {
      pA0n = *reinterpret_cast<const bf16x8*>(pp);
      pA1n = *reinterpret_cast<const bf16x8*>(pp + 32 * 16);
      pp += 64 * 16;
    }
    __syncthreads();
  }

  const long pbase = (long)spz * BB * NG;
#pragma unroll
  for (int r = 0; r < 16; ++r) {
    const int crow = (r & 3) + 8 * (r >> 2) + 4 * hi;
    long rowg = pbase + bNG + row0 + crow;
#pragma unroll
    for (int nt = 0; nt < 4; ++nt)
      part[rowg * DD + nt * 32 + ln] = f2bf(acc[nt][r]);
  }
}

// ---------------------------------------------------------------------------
// post GEMM (surface): out = relu([Ha|Hb] @ W + b), K=256, f32 output.
// ---------------------------------------------------------------------------
__global__ __launch_bounds__(256) void post_mfma_k(
    const unsigned short* __restrict__ Ha, const unsigned short* __restrict__ Hb,
    const unsigned short* __restrict__ Wt, const float* __restrict__ bias,
    float* __restrict__ out, int shift, int mask, int off) {
  int tid = threadIdx.x, l = tid & 63, w = tid >> 6;
  int g = l >> 4, r = l & 15;
  long row0 = (long)blockIdx.x * 64 + w * 16;
  const unsigned short* ha = Ha + (row0 + r) * DD;
  const unsigned short* hb = Hb + (row0 + r) * DD;
  f32x4 z4 = {0.f, 0.f, 0.f, 0.f};
  f32x4 acc[8];
#pragma unroll
  for (int i = 0; i < 8; ++i) acc[i] = z4;
#pragma unroll
  for (int ks = 0; ks < 8; ++ks) {
    const unsigned short* src = (ks < 4) ? (ha + ks * 32) : (hb + (ks - 4) * 32);
    bf16x8 a = *reinterpret_cast<const bf16x8*>(src + 8 * g);
#pragma unroll
    for (int ct = 0; ct < 8; ++ct) {
      bf16x8 b = *reinterpret_cast<const bf16x8*>(Wt + (ct * 16 + r) * 256 +
                                                  ks * 32 + 8 * g);
      acc[ct] = __builtin_amdgcn_mfma_f32_16x16x32_bf16(a, b, acc[ct], 0, 0, 0);
    }
  }
#pragma unroll
  for (int ct = 0; ct < 8; ++ct) {
    float bv = bias[ct * 16 + r];
#pragma unroll
    for (int r4 = 0; r4 < 4; ++r4) {
      long rowg = row0 + 4 * g + r4;
      long bb = rowg >> shift;
      long n = rowg & mask;
      out[(bb * (NS + NG) + off + n) * DD + ct * 16 + r] =
          fmaxf(acc[ct][r4] + bv, 0.f);
    }
  }
}

// ---------------------------------------------------------------------------
// post GEMM (graph) with FUSED split-K reduction: the Hb fragment is the
// f32 sum of the SPLITG msg_g partial slices, rounded once to bf16
// (numerically identical to the former reduce_k -> post chain).
// ---------------------------------------------------------------------------
__global__ __launch_bounds__(256) void post_gr_k(
    const unsigned short* __restrict__ Ha, const unsigned short* __restrict__ part,
    const unsigned short* __restrict__ Wt, const float* __restrict__ bias,
    float* __restrict__ out) {
  int tid = threadIdx.x, l = tid & 63, w = tid >> 6;
  int g = l >> 4, r = l & 15;
  long row0 = (long)blockIdx.x * 64 + w * 16;
  const unsigned short* ha = Ha + (row0 + r) * DD;
  const long S = (long)BB * NG * DD;
  f32x4 z4 = {0.f, 0.f, 0.f, 0.f};
  f32x4 acc[8];
#pragma unroll
  for (int i = 0; i < 8; ++i) acc[i] = z4;
#pragma unroll
  for (int ks = 0; ks < 8; ++ks) {
    bf16x8 a;
    if (ks < 4) {
      a = *reinterpret_cast<const bf16x8*>(ha + ks * 32 + 8 * g);
    } else {
      const unsigned short* pb =
          part + (row0 + r) * DD + (ks - 4) * 32 + 8 * g;
      float s8[8];
#pragma unroll
      for (int k = 0; k < 8; ++k) s8[k] = 0.f;
#pragma unroll
      for (int sp = 0; sp < SPLITG; ++sp) {
        u16x8 v = *reinterpret_cast<const u16x8*>(pb + (long)sp * S);
#pragma unroll
        for (int k = 0; k < 8; ++k) s8[k] += bf2f(v[k]);
      }
#pragma unroll
      for (int k = 0; k < 8; ++k) a[k] = (short)f2bf(s8[k]);
    }
#pragma unroll
    for (int ct = 0; ct < 8; ++ct) {
      bf16x8 b = *reinterpret_cast<const bf16x8*>(Wt + (ct * 16 + r) * 256 +
                                                  ks * 32 + 8 * g);
      acc[ct] = __builtin_amdgcn_mfma_f32_16x16x32_bf16(a, b, acc[ct], 0, 0, 0);
    }
  }
#pragma unroll
  for (int ct = 0; ct < 8; ++ct) {
    float bv = bias[ct * 16 + r];
#pragma unroll
    for (int r4 = 0; r4 < 4; ++r4) {
      long rowg = row0 + 4 * g + r4;
      long bb = rowg >> 11;          // / NG
      long n = rowg & (NG - 1);
      out[(bb * (NS + NG) + NS + n) * DD + ct * 16 + r] =
          fmaxf(acc[ct][r4] + bv, 0.f);
    }
  }
}

// ---------------------------------------------------------------------------
extern "C" void kernel_launch(void* const* d_in, const int* in_sizes, int n_in,
                              void* d_out, int out_size, void* d_ws,
                              size_t ws_size, hipStream_t stream) {
  const float* xs = (const float*)d_in[0];
  const float* xg = (const float*)d_in[1];
  const float* vs = (const float*)d_in[2];
  const float* vg = (const float*)d_in[3];
  const float* Ws_pre = (const float*)d_in[4];
  const float* bs_pre = (const float*)d_in[5];
  const float* Wg_pre = (const float*)d_in[6];
  const float* bg_pre = (const float*)d_in[7];
  const float* Ws_post = (const float*)d_in[8];
  const float* bs_post = (const float*)d_in[9];
  const float* Wg_post = (const float*)d_in[10];
  const float* bg_post = (const float*)d_in[11];
  float* out = (float*)d_out;

  char* p = (char*)d_ws;
  unsigned short* pos1_s = (unsigned short*)p; p += (size_t)BB * NS * 16 * 2;
  unsigned short* pos2_s = (unsigned short*)p; p += (size_t)BB * NS * 16 * 2;
  unsigned short* pos1_g = (unsigned short*)p; p += (size_t)BB * NG * 16 * 2;
  unsigned short* pos2_g = (unsigned short*)p; p += (size_t)BB * NG * 16 * 2;
  unsigned short* WtS_pre = (unsigned short*)p; p += (size_t)128 * 128 * 2;
  unsigned short* WtG_pre = (unsigned short*)p; p += (size_t)128 * 128 * 2;
  unsigned short* WtS_post = (unsigned short*)p; p += (size_t)128 * 256 * 2;
  unsigned short* WtG_post = (unsigned short*)p; p += (size_t)128 * 256 * 2;
  unsigned short* xg_h = (unsigned short*)p; p += (size_t)BB * NG * DD * 2;
  unsigned short* xg_hT = (unsigned short*)p; p += (size_t)BB * NG * DD * 2;
  unsigned short* xs_hT = (unsigned short*)p; p += (size_t)BB * NS * DD * 2;
  unsigned short* xg_o = (unsigned short*)p; p += (size_t)BB * NG * DD * 2;
  (void)xg_o;  // retired (reduction fused into post_gr_k); slot kept for layout
  float* rsinv = (float*)p; p += (size_t)BB * NS * 4;
  // region R: [xs_h | xs_o] — dead after post_s — reused as msg_g partials
  unsigned short* xs_h = (unsigned short*)p;
  unsigned short* xs_o = xs_h + (size_t)BB * NS * DD;
  unsigned short* part_g = xs_h;  // SPLITG * BB*NG*DD = 2 * BB*NS*DD exactly
  p += (size_t)2 * BB * NS * DD * 2;

  prep_k<<<(BB * (NS + NG)) / 256 + 98304 / 256, 256, 0, stream>>>(
      vs, vg, Ws_pre, Wg_pre, Ws_post, Wg_post, pos1_s, pos2_s, pos1_g,
      pos2_g, WtS_pre, WtG_pre, WtS_post, WtG_post);
  pre_mfma_k<<<(BB * NS + BB * NG) / 64, 256, 0, stream>>>(
      xs, xg, WtS_pre, WtG_pre, bs_pre, bg_pre, xs_h, xg_h);
  transpose_k<<<BB * NG / 64, 256, 0, stream>>>(xg_h, xg_hT, BB * NG, nullptr);
  msg_s_k<<<dim3(NS / 128, BB), 256, 0, stream>>>(pos1_g, pos2_s, xg_hT, xs_o,
                                                  rsinv);
  transpose_k<<<BB * NS / 64, 256, 0, stream>>>(xs_h, xs_hT, BB * NS, rsinv);
  post_mfma_k<<<BB * NS / 64, 256, 0, stream>>>(xs_h, xs_o, WtS_post, bs_post,
                                                out, 14, NS - 1, 0);
  msg_g_k<<<dim3(NG / 128, BB, SPLITG), 256, 0, stream>>>(pos1_s, pos2_g,
                                                          xs_hT, part_g);
  post_gr_k<<<BB * NG / 64, 256, 0, stream>>>(xg_h, part_g, WtG_post, bg_post,
                                              out);
}

// Round 11
// 204.113 us; speedup vs baseline: 1.0199x; 1.0032x over previous
//
#include <hip/hip_runtime.h>
#include <hip/hip_bf16.h>

#define BB 4
#define NS 16384
#define NG 2048
#define DD 128
#define SPLITG 16
#define C2F (-0.23083120f)  // -log2(e)/sigma^2

typedef short bf16x8 __attribute__((ext_vector_type(8)));
typedef unsigned short u16x8 __attribute__((ext_vector_type(8)));
typedef float f32x4 __attribute__((ext_vector_type(4)));
typedef float f32x16 __attribute__((ext_vector_type(16)));
typedef int i32x4 __attribute__((ext_vector_type(4)));

// exp2: builtin (compiler-known hazards) or libcall. NEVER naked asm.
#if __has_builtin(__builtin_amdgcn_exp2f)
#define EXP2(x) __builtin_amdgcn_exp2f(x)
#else
#define EXP2(x) exp2f(x)
#endif

__device__ __forceinline__ unsigned short f2bf(float x) {
  unsigned int u = __builtin_bit_cast(unsigned int, x);
  u += 0x7FFFu + ((u >> 16) & 1u);
  return (unsigned short)(u >> 16);
}
__device__ __forceinline__ float bf2f(unsigned short h) {
  unsigned int u = ((unsigned int)h) << 16;
  return __builtin_bit_cast(float, u);
}

// pack 8 f32 -> bf16x8 A-fragment via cvt_pk + permlane32_swap (T12 recipe).
// HARDENED single asm block (earlyclobbers + s_nop guards) — r8/r10-verified.
#define PACK_SWAP(e0, e1, e2, e3, e4, e5, e6, e7, OUT)                        \
  {                                                                           \
    unsigned pq0, pq1, pq2, pq3;                                              \
    asm("v_cvt_pk_bf16_f32 %0, %4, %5\n\t"                                    \
        "v_cvt_pk_bf16_f32 %1, %6, %7\n\t"                                    \
        "v_cvt_pk_bf16_f32 %2, %8, %9\n\t"                                    \
        "v_cvt_pk_bf16_f32 %3, %10, %11\n\t"                                  \
        "s_nop 1\n\t"                                                         \
        "v_permlane32_swap_b32 %0, %2\n\t"                                    \
        "v_permlane32_swap_b32 %1, %3\n\t"                                    \
        "s_nop 1"                                                             \
        : "=&v"(pq0), "=&v"(pq1), "=&v"(pq2), "=&v"(pq3)                      \
        : "v"(e0), "v"(e1), "v"(e2), "v"(e3), "v"(e4), "v"(e5), "v"(e6),      \
          "v"(e7));                                                           \
    i32x4 tmp_ = {(int)pq0, (int)pq1, (int)pq2, (int)pq3};                    \
    OUT = __builtin_bit_cast(bf16x8, tmp_);                                   \
  }

// ---------------------------------------------------------------------------
// prep: node pos encodings (UNSCALED verified form: dot(pos1,pos2)=d2, hi/lo
// split) + weight transposes, fused into one launch.
// ---------------------------------------------------------------------------
__device__ __forceinline__ void posprep1(const float* __restrict__ v, int i,
                                         unsigned short* __restrict__ pos1,
                                         unsigned short* __restrict__ pos2) {
  float x = v[i * 3 + 0], y = v[i * 3 + 1], z = v[i * 3 + 2];
  unsigned short hx = f2bf(x), hy = f2bf(y), hz = f2bf(z);
  float fx = bf2f(hx), fy = bf2f(hy), fz = bf2f(hz);
  unsigned short lx = f2bf(x - fx), ly = f2bf(y - fy), lz = f2bf(z - fz);
  float n = x * x + y * y + z * z;
  unsigned short nh = f2bf(n);
  unsigned short nl = f2bf(n - bf2f(nh));
  unsigned short m2hx = f2bf(-2.f * fx), m2hy = f2bf(-2.f * fy),
                 m2hz = f2bf(-2.f * fz);
  unsigned short m2lx = f2bf(-2.f * bf2f(lx)), m2ly = f2bf(-2.f * bf2f(ly)),
                 m2lz = f2bf(-2.f * bf2f(lz));
  const unsigned short one = 0x3F80;
  u16x8 a0 = {m2hx, m2hy, m2hz, m2lx, m2ly, m2lz, m2hx, m2hy};
  u16x8 a1 = {m2hz, m2lx, m2ly, m2lz, nh, nl, one, one};
  u16x8 b0 = {hx, hy, hz, hx, hy, hz, lx, ly};
  u16x8 b1 = {lz, lx, ly, lz, one, one, nh, nl};
  *(u16x8*)(pos1 + (long)i * 16) = a0;
  *(u16x8*)(pos1 + (long)i * 16 + 8) = a1;
  *(u16x8*)(pos2 + (long)i * 16) = b0;
  *(u16x8*)(pos2 + (long)i * 16 + 8) = b1;
}

__global__ __launch_bounds__(256) void prep_k(
    const float* __restrict__ vs, const float* __restrict__ vg,
    const float* __restrict__ Ws_pre, const float* __restrict__ Wg_pre,
    const float* __restrict__ Ws_post, const float* __restrict__ Wg_post,
    unsigned short* __restrict__ pos1_s, unsigned short* __restrict__ pos2_s,
    unsigned short* __restrict__ pos1_g, unsigned short* __restrict__ pos2_g,
    unsigned short* __restrict__ WtS_pre, unsigned short* __restrict__ WtG_pre,
    unsigned short* __restrict__ WtS_post,
    unsigned short* __restrict__ WtG_post) {
  const int NODEBLK = (BB * (NS + NG)) / 256;  // 288
  int bid = blockIdx.x, tid = threadIdx.x;
  if (bid < NODEBLK) {
    int i = bid * 256 + tid;
    if (i < BB * NS)
      posprep1(vs, i, pos1_s, pos2_s);
    else
      posprep1(vg, i - BB * NS, pos1_g, pos2_g);
  } else {
    int k2 = (bid - NODEBLK) * 256 + tid;
    const float* W;
    unsigned short* Wt;
    int kshift, loc;
    if (k2 < 16384) { W = Ws_pre; Wt = WtS_pre; kshift = 7; loc = k2; }
    else if (k2 < 32768) { W = Wg_pre; Wt = WtG_pre; kshift = 7; loc = k2 - 16384; }
    else if (k2 < 65536) { W = Ws_post; Wt = WtS_post; kshift = 8; loc = k2 - 32768; }
    else { W = Wg_post; Wt = WtG_post; kshift = 8; loc = k2 - 65536; }
    int K = 1 << kshift;
    int e = loc >> kshift, k = loc & (K - 1);
    Wt[(long)e * K + k] = f2bf(W[(long)k * 128 + e]);
  }
}

// ---------------------------------------------------------------------------
// pre GEMM (surface + graph fused): H = relu(X @ W + b), K=128.
// ---------------------------------------------------------------------------
__global__ __launch_bounds__(256) void pre_mfma_k(
    const float* __restrict__ xs, const float* __restrict__ xg,
    const unsigned short* __restrict__ WtS,
    const unsigned short* __restrict__ WtG, const float* __restrict__ bs,
    const float* __restrict__ bg, unsigned short* __restrict__ xs_h,
    unsigned short* __restrict__ xg_h) {
  long r0 = (long)blockIdx.x * 64;
  const float* X;
  const unsigned short* Wt;
  const float* bias;
  unsigned short* H;
  long row0;
  if (r0 < (long)BB * NS) {
    X = xs; Wt = WtS; bias = bs; H = xs_h; row0 = r0;
  } else {
    X = xg; Wt = WtG; bias = bg; H = xg_h; row0 = r0 - (long)BB * NS;
  }
  int tid = threadIdx.x, l = tid & 63, w = tid >> 6;
  int g = l >> 4, r = l & 15;
  row0 += w * 16;
  const float* xrow = X + (row0 + r) * DD;
  f32x4 z4 = {0.f, 0.f, 0.f, 0.f};
  f32x4 acc[8];
#pragma unroll
  for (int i = 0; i < 8; ++i) acc[i] = z4;
#pragma unroll
  for (int ks = 0; ks < 4; ++ks) {
    float4 v0 = *(const float4*)(xrow + ks * 32 + 8 * g);
    float4 v1 = *(const float4*)(xrow + ks * 32 + 8 * g + 4);
    bf16x8 a;
    a[0] = (short)f2bf(v0.x); a[1] = (short)f2bf(v0.y);
    a[2] = (short)f2bf(v0.z); a[3] = (short)f2bf(v0.w);
    a[4] = (short)f2bf(v1.x); a[5] = (short)f2bf(v1.y);
    a[6] = (short)f2bf(v1.z); a[7] = (short)f2bf(v1.w);
#pragma unroll
    for (int ct = 0; ct < 8; ++ct) {
      bf16x8 b = *reinterpret_cast<const bf16x8*>(Wt + (ct * 16 + r) * DD +
                                                  ks * 32 + 8 * g);
      acc[ct] = __builtin_amdgcn_mfma_f32_16x16x32_bf16(a, b, acc[ct], 0, 0, 0);
    }
  }
#pragma unroll
  for (int ct = 0; ct < 8; ++ct) {
    float bv = bias[ct * 16 + r];
#pragma unroll
    for (int r4 = 0; r4 < 4; ++r4) {
      long row = row0 + 4 * g + r4;
      H[row * DD + ct * 16 + r] = f2bf(fmaxf(acc[ct][r4] + bv, 0.f));
    }
  }
}

// ---------------------------------------------------------------------------
// bf16 [R][128] -> [128][R], optional per-row scale (rsinv fold for msg_g)
// ---------------------------------------------------------------------------
__global__ __launch_bounds__(256) void transpose_k(
    const unsigned short* __restrict__ H, unsigned short* __restrict__ HT,
    int R, const float* __restrict__ scale) {
  __shared__ unsigned short lds[64 * 136];
  int tid = threadIdx.x;
  long r0 = (long)blockIdx.x * 64;
#pragma unroll
  for (int q = 0; q < 4; ++q) {
    int idx = q * 2048 + tid * 8;
    int rr = idx >> 7, cc = idx & 127;
    u16x8 v = *reinterpret_cast<const u16x8*>(H + (r0 + rr) * 128 + cc);
    if (scale) {
      float s = scale[r0 + rr];
#pragma unroll
      for (int i = 0; i < 8; ++i) v[i] = f2bf(bf2f(v[i]) * s);
    }
    *(u16x8*)&lds[rr * 136 + cc] = v;
  }
  __syncthreads();
  int e = tid >> 1, half = tid & 1;
#pragma unroll
  for (int q = 0; q < 4; ++q) {
    u16x8 v;
#pragma unroll
    for (int i = 0; i < 8; ++i)
      v[i] = lds[(half * 32 + q * 8 + i) * 136 + e];
    *reinterpret_cast<u16x8*>(HT + (long)e * R + r0 + half * 32 + q * 8) = v;
  }
}

// ---------------------------------------------------------------------------
// msg_s: block = 128 surface rows (4 waves x 32). Streams Ng in 64-col chunks.
// Swapped pos MFMA (32x32x16) -> d2 in regs -> v_exp(d2*C2) -> cvt_pk+permlane
// -> msg MFMA A-frags. Features [128][64] in LDS, slot^f&7 swizzle, dbuf.
// r10-verified structure; the two pos MFMAs per chunk are DUAL-ISSUED (S0,S1
// independent) so exp(S0) overlaps S1's MFMA latency.
// ---------------------------------------------------------------------------
__global__ __launch_bounds__(256) void msg_s_k(
    const unsigned short* __restrict__ pos1_g,
    const unsigned short* __restrict__ pos2_s,
    const unsigned short* __restrict__ xg_hT, unsigned short* __restrict__ xs_o,
    float* __restrict__ rsinv) {
  __shared__ __align__(16) unsigned short ldsB[2][128 * 64];
  const int tid = threadIdx.x;
  const int w = tid >> 6, l = tid & 63;
  const int ln = l & 31, hi = l >> 5;
  const int b = blockIdx.y;
  const long bNS = (long)b * NS, bNG = (long)b * NG;
  const long row0 = (long)blockIdx.x * 128 + w * 32;
  const long BNG = (long)BB * NG;
  const int NCH = NG / 64;

  const bf16x8 bP = *reinterpret_cast<const bf16x8*>(
      pos2_s + (bNS + row0 + ln) * 16 + 8 * hi);

  const f32x16 zz = {0.f, 0.f, 0.f, 0.f, 0.f, 0.f, 0.f, 0.f,
                     0.f, 0.f, 0.f, 0.f, 0.f, 0.f, 0.f, 0.f};
  f32x16 acc[4] = {zz, zz, zz, zz};
  float rs0 = 0.f, rs1 = 0.f, rs2 = 0.f, rs3 = 0.f;

  const int tf = tid >> 3;
  const int tsp = tid & 7;
  const unsigned short* p0 = xg_hT + (long)tf * BNG + bNG + (tsp ^ (tf & 7)) * 8;
  const unsigned short* p1 = p0 + (long)32 * BNG;
  const unsigned short* p2 = p0 + (long)64 * BNG;
  const unsigned short* p3 = p0 + (long)96 * BNG;
  const unsigned short* pp = pos1_g + (bNG + ln) * 16 + 8 * hi;

  u16x8 stA[4];
  bf16x8 pA0, pA1, pA0n, pA1n;
  stA[0] = *reinterpret_cast<const u16x8*>(p0);
  stA[1] = *reinterpret_cast<const u16x8*>(p1);
  stA[2] = *reinterpret_cast<const u16x8*>(p2);
  stA[3] = *reinterpret_cast<const u16x8*>(p3);
#pragma unroll
  for (int q = 0; q < 4; ++q)
    *(u16x8*)&ldsB[0][(q * 32 + tf) * 64 + tsp * 8] = stA[q];
  stA[0] = *reinterpret_cast<const u16x8*>(p0 + 64);
  stA[1] = *reinterpret_cast<const u16x8*>(p1 + 64);
  stA[2] = *reinterpret_cast<const u16x8*>(p2 + 64);
  stA[3] = *reinterpret_cast<const u16x8*>(p3 + 64);
  p0 += 128; p1 += 128; p2 += 128; p3 += 128;
  pA0 = *reinterpret_cast<const bf16x8*>(pp);
  pA1 = *reinterpret_cast<const bf16x8*>(pp + 32 * 16);
  pA0n = *reinterpret_cast<const bf16x8*>(pp + 64 * 16);
  pA1n = *reinterpret_cast<const bf16x8*>(pp + 96 * 16);
  pp += 128 * 16;
  __syncthreads();

#pragma unroll 1
  for (int c = 0; c < NCH; ++c) {
    const int buf = c & 1;
    float ex[2][16];
    bf16x8 fr[2][2];
    // dual-issue both pos MFMAs; exp(S0) overlaps S1's MFMA latency
    f32x16 S0 = __builtin_amdgcn_mfma_f32_32x32x16_bf16(pA0, bP, zz, 0, 0, 0);
    f32x16 S1 = __builtin_amdgcn_mfma_f32_32x32x16_bf16(pA1, bP, zz, 0, 0, 0);
#pragma unroll
    for (int r = 0; r < 16; ++r) ex[0][r] = EXP2(S0[r] * C2F);
    PACK_SWAP(ex[0][0], ex[0][1], ex[0][2], ex[0][3], ex[0][4], ex[0][5],
              ex[0][6], ex[0][7], fr[0][0]);
    PACK_SWAP(ex[0][8], ex[0][9], ex[0][10], ex[0][11], ex[0][12], ex[0][13],
              ex[0][14], ex[0][15], fr[0][1]);
#pragma unroll
    for (int r = 0; r < 16; ++r) ex[1][r] = EXP2(S1[r] * C2F);
    PACK_SWAP(ex[1][0], ex[1][1], ex[1][2], ex[1][3], ex[1][4], ex[1][5],
              ex[1][6], ex[1][7], fr[1][0]);
    PACK_SWAP(ex[1][8], ex[1][9], ex[1][10], ex[1][11], ex[1][12], ex[1][13],
              ex[1][14], ex[1][15], fr[1][1]);
#pragma unroll
    for (int r = 0; r < 4; ++r) {
      rs0 += ex[0][r] + ex[1][r];
      rs1 += ex[0][r + 4] + ex[1][r + 4];
      rs2 += ex[0][r + 8] + ex[1][r + 8];
      rs3 += ex[0][r + 12] + ex[1][r + 12];
    }
#pragma unroll
    for (int t2 = 0; t2 < 2; ++t2) {
#pragma unroll
      for (int kh = 0; kh < 2; ++kh) {
        const int kt = t2 * 2 + kh;
        const int spr = ((kt * 2 + hi) ^ (ln & 7)) * 8;
#pragma unroll
        for (int nt = 0; nt < 4; ++nt) {
          const bf16x8 bm = *reinterpret_cast<const bf16x8*>(
              &ldsB[buf][(nt * 32 + ln) * 64 + spr]);
          acc[nt] = __builtin_amdgcn_mfma_f32_32x32x16_bf16(fr[t2][kh], bm,
                                                            acc[nt], 0, 0, 0);
        }
      }
    }
    if (c + 1 < NCH) {
#pragma unroll
      for (int q = 0; q < 4; ++q)
        *(u16x8*)&ldsB[buf ^ 1][(q * 32 + tf) * 64 + tsp * 8] = stA[q];
    }
    if (c + 2 < NCH) {
      stA[0] = *reinterpret_cast<const u16x8*>(p0);
      stA[1] = *reinterpret_cast<const u16x8*>(p1);
      stA[2] = *reinterpret_cast<const u16x8*>(p2);
      stA[3] = *reinterpret_cast<const u16x8*>(p3);
      p0 += 64; p1 += 64; p2 += 64; p3 += 64;
    }
    pA0 = pA0n;
    pA1 = pA1n;
    if (c + 2 < NCH) {
      pA0n = *reinterpret_cast<const bf16x8*>(pp);
      pA1n = *reinterpret_cast<const bf16x8*>(pp + 32 * 16);
      pp += 64 * 16;
    }
    __syncthreads();
  }

  float rtot = (rs0 + rs1) + (rs2 + rs3);
  rtot += __shfl_xor(rtot, 32, 64);
  float denom = rtot + 1e-8f;
  float rsi = 1.f / denom;
  if (hi == 0) rsinv[bNS + row0 + ln] = rsi;
#pragma unroll
  for (int r = 0; r < 16; ++r) {
    const int crow = (r & 3) + 8 * (r >> 2) + 4 * hi;
    float rsib = __shfl(rsi, crow, 64);
    long rowg = bNS + row0 + crow;
#pragma unroll
    for (int nt = 0; nt < 4; ++nt)
      xs_o[rowg * DD + nt * 32 + ln] = f2bf(acc[nt][r] * rsib);
  }
}

// ---------------------------------------------------------------------------
// msg_g: block = 128 graph rows (4 waves x 32). Streams its 1/SPLITG of Ns.
// xs_hT pre-scaled by rsinv. Same dual-issue of S0/S1.
// ---------------------------------------------------------------------------
__global__ __launch_bounds__(256) void msg_g_k(
    const unsigned short* __restrict__ pos1_s,
    const unsigned short* __restrict__ pos2_g,
    const unsigned short* __restrict__ xs_hT, unsigned short* __restrict__ part) {
  __shared__ __align__(16) unsigned short ldsB[2][128 * 64];
  const int tid = threadIdx.x;
  const int w = tid >> 6, l = tid & 63;
  const int ln = l & 31, hi = l >> 5;
  const int b = blockIdx.y, spz = blockIdx.z;
  const long bNS = (long)b * NS, bNG = (long)b * NG;
  const long nbeg = (long)spz * (NS / SPLITG);
  const long row0 = (long)blockIdx.x * 128 + w * 32;
  const long BNS = (long)BB * NS;
  const int NCH = (NS / SPLITG) / 64;

  const bf16x8 bP = *reinterpret_cast<const bf16x8*>(
      pos2_g + (bNG + row0 + ln) * 16 + 8 * hi);

  const f32x16 zz = {0.f, 0.f, 0.f, 0.f, 0.f, 0.f, 0.f, 0.f,
                     0.f, 0.f, 0.f, 0.f, 0.f, 0.f, 0.f, 0.f};
  f32x16 acc[4] = {zz, zz, zz, zz};

  const int tf = tid >> 3;
  const int tsp = tid & 7;
  const unsigned short* p0 = xs_hT + (long)tf * BNS + bNS + nbeg +
                             (tsp ^ (tf & 7)) * 8;
  const unsigned short* p1 = p0 + (long)32 * BNS;
  const unsigned short* p2 = p0 + (long)64 * BNS;
  const unsigned short* p3 = p0 + (long)96 * BNS;
  const unsigned short* pp = pos1_s + (bNS + nbeg + ln) * 16 + 8 * hi;

  u16x8 stA[4];
  bf16x8 pA0, pA1, pA0n, pA1n;
  stA[0] = *reinterpret_cast<const u16x8*>(p0);
  stA[1] = *reinterpret_cast<const u16x8*>(p1);
  stA[2] = *reinterpret_cast<const u16x8*>(p2);
  stA[3] = *reinterpret_cast<const u16x8*>(p3);
#pragma unroll
  for (int q = 0; q < 4; ++q)
    *(u16x8*)&ldsB[0][(q * 32 + tf) * 64 + tsp * 8] = stA[q];
  stA[0] = *reinterpret_cast<const u16x8*>(p0 + 64);
  stA[1] = *reinterpret_cast<const u16x8*>(p1 + 64);
  stA[2] = *reinterpret_cast<const u16x8*>(p2 + 64);
  stA[3] = *reinterpret_cast<const u16x8*>(p3 + 64);
  p0 += 128; p1 += 128; p2 += 128; p3 += 128;
  pA0 = *reinterpret_cast<const bf16x8*>(pp);
  pA1 = *reinterpret_cast<const bf16x8*>(pp + 32 * 16);
  pA0n = *reinterpret_cast<const bf16x8*>(pp + 64 * 16);
  pA1n = *reinterpret_cast<const bf16x8*>(pp + 96 * 16);
  pp += 128 * 16;
  __syncthreads();

#pragma unroll 1
  for (int c = 0; c < NCH; ++c) {
    const int buf = c & 1;
    float ex[2][16];
    bf16x8 fr[2][2];
    f32x16 S0 = __builtin_amdgcn_mfma_f32_32x32x16_bf16(pA0, bP, zz, 0, 0, 0);
    f32x16 S1 = __builtin_amdgcn_mfma_f32_32x32x16_bf16(pA1, bP, zz, 0, 0, 0);
#pragma unroll
    for (int r = 0; r < 16; ++r) ex[0][r] = EXP2(S0[r] * C2F);
    PACK_SWAP(ex[0][0], ex[0][1], ex[0][2], ex[0][3], ex[0][4], ex[0][5],
              ex[0][6], ex[0][7], fr[0][0]);
    PACK_SWAP(ex[0][8], ex[0][9], ex[0][10], ex[0][11], ex[0][12], ex[0][13],
              ex[0][14], ex[0][15], fr[0][1]);
#pragma unroll
    for (int r = 0; r < 16; ++r) ex[1][r] = EXP2(S1[r] * C2F);
    PACK_SWAP(ex[1][0], ex[1][1], ex[1][2], ex[1][3], ex[1][4], ex[1][5],
              ex[1][6], ex[1][7], fr[1][0]);
    PACK_SWAP(ex[1][8], ex[1][9], ex[1][10], ex[1][11], ex[1][12], ex[1][13],
              ex[1][14], ex[1][15], fr[1][1]);
#pragma unroll
    for (int t2 = 0; t2 < 2; ++t2) {
#pragma unroll
      for (int kh = 0; kh < 2; ++kh) {
        const int kt = t2 * 2 + kh;
        const int spr = ((kt * 2 + hi) ^ (ln & 7)) * 8;
#pragma unroll
        for (int nt = 0; nt < 4; ++nt) {
          const bf16x8 bm = *reinterpret_cast<const bf16x8*>(
              &ldsB[buf][(nt * 32 + ln) * 64 + spr]);
          acc[nt] = __builtin_amdgcn_mfma_f32_32x32x16_bf16(fr[t2][kh], bm,
                                                            acc[nt], 0, 0, 0);
        }
      }
    }
    if (c + 1 < NCH) {
#pragma unroll
      for (int q = 0; q < 4; ++q)
        *(u16x8*)&ldsB[buf ^ 1][(q * 32 + tf) * 64 + tsp * 8] = stA[q];
    }
    if (c + 2 < NCH) {
      stA[0] = *reinterpret_cast<const u16x8*>(p0);
      stA[1] = *reinterpret_cast<const u16x8*>(p1);
      stA[2] = *reinterpret_cast<const u16x8*>(p2);
      stA[3] = *reinterpret_cast<const u16x8*>(p3);
      p0 += 64; p1 += 64; p2 += 64; p3 += 64;
    }
    pA0 = pA0n;
    pA1 = pA1n;
    if (c + 2 < NCH) {
      pA0n = *reinterpret_cast<const bf16x8*>(pp);
      pA1n = *reinterpret_cast<const bf16x8*>(pp + 32 * 16);
      pp += 64 * 16;
    }
    __syncthreads();
  }

  const long pbase = (long)spz * BB * NG;
#pragma unroll
  for (int r = 0; r < 16; ++r) {
    const int crow = (r & 3) + 8 * (r >> 2) + 4 * hi;
    long rowg = pbase + bNG + row0 + crow;
#pragma unroll
    for (int nt = 0; nt < 4; ++nt)
      part[rowg * DD + nt * 32 + ln] = f2bf(acc[nt][r]);
  }
}

__global__ __launch_bounds__(256) void reduce_k(
    const unsigned short* __restrict__ part, unsigned short* __restrict__ xg_o) {
  long i = ((long)blockIdx.x * 256 + threadIdx.x) * 8;
  const long S = (long)BB * NG * DD;
  float a[8];
#pragma unroll
  for (int k = 0; k < 8; ++k) a[k] = 0.f;
#pragma unroll
  for (int s = 0; s < SPLITG; ++s) {
    u16x8 v = *reinterpret_cast<const u16x8*>(part + s * S + i);
#pragma unroll
    for (int k = 0; k < 8; ++k) a[k] += bf2f(v[k]);
  }
  u16x8 o;
#pragma unroll
  for (int k = 0; k < 8; ++k) o[k] = f2bf(a[k]);
  *reinterpret_cast<u16x8*>(xg_o + i) = o;
}

// ---------------------------------------------------------------------------
// post GEMM: out = relu([Ha|Hb] @ W + b), K=256, f32 output.
// ---------------------------------------------------------------------------
__global__ __launch_bounds__(256) void post_mfma_k(
    const unsigned short* __restrict__ Ha, const unsigned short* __restrict__ Hb,
    const unsigned short* __restrict__ Wt, const float* __restrict__ bias,
    float* __restrict__ out, int shift, int mask, int off) {
  int tid = threadIdx.x, l = tid & 63, w = tid >> 6;
  int g = l >> 4, r = l & 15;
  long row0 = (long)blockIdx.x * 64 + w * 16;
  const unsigned short* ha = Ha + (row0 + r) * DD;
  const unsigned short* hb = Hb + (row0 + r) * DD;
  f32x4 z4 = {0.f, 0.f, 0.f, 0.f};
  f32x4 acc[8];
#pragma unroll
  for (int i = 0; i < 8; ++i) acc[i] = z4;
#pragma unroll
  for (int ks = 0; ks < 8; ++ks) {
    const unsigned short* src = (ks < 4) ? (ha + ks * 32) : (hb + (ks - 4) * 32);
    bf16x8 a = *reinterpret_cast<const bf16x8*>(src + 8 * g);
#pragma unroll
    for (int ct = 0; ct < 8; ++ct) {
      bf16x8 b = *reinterpret_cast<const bf16x8*>(Wt + (ct * 16 + r) * 256 +
                                                  ks * 32 + 8 * g);
      acc[ct] = __builtin_amdgcn_mfma_f32_16x16x32_bf16(a, b, acc[ct], 0, 0, 0);
    }
  }
#pragma unroll
  for (int ct = 0; ct < 8; ++ct) {
    float bv = bias[ct * 16 + r];
#pragma unroll
    for (int r4 = 0; r4 < 4; ++r4) {
      long rowg = row0 + 4 * g + r4;
      long bb = rowg >> shift;
      long n = rowg & mask;
      out[(bb * (NS + NG) + off + n) * DD + ct * 16 + r] =
          fmaxf(acc[ct][r4] + bv, 0.f);
    }
  }
}

// ---------------------------------------------------------------------------
extern "C" void kernel_launch(void* const* d_in, const int* in_sizes, int n_in,
                              void* d_out, int out_size, void* d_ws,
                              size_t ws_size, hipStream_t stream) {
  const float* xs = (const float*)d_in[0];
  const float* xg = (const float*)d_in[1];
  const float* vs = (const float*)d_in[2];
  const float* vg = (const float*)d_in[3];
  const float* Ws_pre = (const float*)d_in[4];
  const float* bs_pre = (const float*)d_in[5];
  const float* Wg_pre = (const float*)d_in[6];
  const float* bg_pre = (const float*)d_in[7];
  const float* Ws_post = (const float*)d_in[8];
  const float* bs_post = (const float*)d_in[9];
  const float* Wg_post = (const float*)d_in[10];
  const float* bg_post = (const float*)d_in[11];
  float* out = (float*)d_out;

  char* p = (char*)d_ws;
  unsigned short* pos1_s = (unsigned short*)p; p += (size_t)BB * NS * 16 * 2;
  unsigned short* pos2_s = (unsigned short*)p; p += (size_t)BB * NS * 16 * 2;
  unsigned short* pos1_g = (unsigned short*)p; p += (size_t)BB * NG * 16 * 2;
  unsigned short* pos2_g = (unsigned short*)p; p += (size_t)BB * NG * 16 * 2;
  unsigned short* WtS_pre = (unsigned short*)p; p += (size_t)128 * 128 * 2;
  unsigned short* WtG_pre = (unsigned short*)p; p += (size_t)128 * 128 * 2;
  unsigned short* WtS_post = (unsigned short*)p; p += (size_t)128 * 256 * 2;
  unsigned short* WtG_post = (unsigned short*)p; p += (size_t)128 * 256 * 2;
  unsigned short* xg_h = (unsigned short*)p; p += (size_t)BB * NG * DD * 2;
  unsigned short* xg_hT = (unsigned short*)p; p += (size_t)BB * NG * DD * 2;
  unsigned short* xs_hT = (unsigned short*)p; p += (size_t)BB * NS * DD * 2;
  unsigned short* xg_o = (unsigned short*)p; p += (size_t)BB * NG * DD * 2;
  float* rsinv = (float*)p; p += (size_t)BB * NS * 4;
  // region R: [xs_h | xs_o] — dead after post_s — reused as msg_g partials
  unsigned short* xs_h = (unsigned short*)p;
  unsigned short* xs_o = xs_h + (size_t)BB * NS * DD;
  unsigned short* part_g = xs_h;  // SPLITG * BB*NG*DD = 2 * BB*NS*DD exactly
  p += (size_t)2 * BB * NS * DD * 2;

  prep_k<<<(BB * (NS + NG)) / 256 + 98304 / 256, 256, 0, stream>>>(
      vs, vg, Ws_pre, Wg_pre, Ws_post, Wg_post, pos1_s, pos2_s, pos1_g,
      pos2_g, WtS_pre, WtG_pre, WtS_post, WtG_post);
  pre_mfma_k<<<(BB * NS + BB * NG) / 64, 256, 0, stream>>>(
      xs, xg, WtS_pre, WtG_pre, bs_pre, bg_pre, xs_h, xg_h);
  transpose_k<<<BB * NG / 64, 256, 0, stream>>>(xg_h, xg_hT, BB * NG, nullptr);
  msg_s_k<<<dim3(NS / 128, BB), 256, 0, stream>>>(pos1_g, pos2_s, xg_hT, xs_o,
                                                  rsinv);
  transpose_k<<<BB * NS / 64, 256, 0, stream>>>(xs_h, xs_hT, BB * NS, rsinv);
  post_mfma_k<<<BB * NS / 64, 256, 0, stream>>>(xs_h, xs_o, WtS_post, bs_post,
                                                out, 14, NS - 1, 0);
  msg_g_k<<<dim3(NG / 128, BB, SPLITG), 256, 0, stream>>>(pos1_s, pos2_g,
                                                          xs_hT, part_g);
  reduce_k<<<(BB * NG * DD) / 8 / 256, 256, 0, stream>>>(part_g, xg_o);
  post_mfma_k<<<BB * NG / 64, 256, 0, stream>>>(xg_h, xg_o, WtG_post, bg_post,
                                                out, 11, NG - 1, NS);
}